// Round 3
// baseline (585.004 us; speedup 1.0000x reference)
//
#include <hip/hip_runtime.h>

// Round-4 = round-3 retry: __builtin_nontemporal_load/store reject HIP's
// float4 (HIP_vector_type class); they need clang native vectors. Use
// ext_vector_type(4) for every nontemporal access. Structure unchanged:
//
// Analysis recap: three structures (LDS-staged, direct, grid-stride
// lane-local) all plateau at ~165 us / 1.8 TB/s HBM, VALUBusy 15%,
// occupancy 60%, FETCH_SIZE ~= half the input (50/50 L3 hit/miss from
// streaming 512 MiB of zero-reuse data through the 256-MiB L3, allocating
// every line). Aggregate L3+HBM service stuck at 3.4 TB/s.
// Mechanism under test: nontemporal (nt) loads/stores stop allocating the
// streams in cache; 2 image-groups/iter -> 8 loads in flight per lane;
// contiguous 64-KiB per-wave regions for long sequential DRAM runs.
//
// Compute decomposition (verified passing, absmax 4.8e-7): 1 lane = 1
// quadrant of 1 image; matmul1 lane-local (Wc addresses uniform -> SGPR);
// matmul2 partial per quadrant, summed across the 4 quadrant lanes via
// shfl_xor(1)+shfl_xor(2); lane p==0 stores the final float4.

typedef float fx4 __attribute__((ext_vector_type(4)));

static __device__ __forceinline__ fx4 ntload4(const fx4* __restrict__ p) {
    return __builtin_nontemporal_load(p);
}

// Full per-quadrant forward pass. v0..v3 = quadrant rows 0..3.
// Returns clipped final vector (valid in lane p==0 of each 4-lane quad).
static __device__ __forceinline__ fx4 forward_quad(
    fx4 v0, fx4 v1, fx4 v2, fx4 v3,
    const float4* __restrict__ wc4,
    float4 wl0, float4 wl1, float4 wl2, float4 wl3)
{
    const fx4 vv[4] = {v0, v1, v2, v3};
    float ax = 0.f, ay = 0.f, az = 0.f, aw = 0.f;
#pragma unroll
    for (int j = 0; j < 4; ++j) {
        const fx4 v = vv[j];
        const float4 w0 = wc4[4 * j + 0];   // uniform address -> s_load
        const float4 w1 = wc4[4 * j + 1];
        const float4 w2 = wc4[4 * j + 2];
        const float4 w3 = wc4[4 * j + 3];
        ax = fmaf(v.x, w0.x, ax); ay = fmaf(v.x, w0.y, ay);
        az = fmaf(v.x, w0.z, az); aw = fmaf(v.x, w0.w, aw);
        ax = fmaf(v.y, w1.x, ax); ay = fmaf(v.y, w1.y, ay);
        az = fmaf(v.y, w1.z, az); aw = fmaf(v.y, w1.w, aw);
        ax = fmaf(v.z, w2.x, ax); ay = fmaf(v.z, w2.y, ay);
        az = fmaf(v.z, w2.z, az); aw = fmaf(v.z, w2.w, aw);
        ax = fmaf(v.w, w3.x, ax); ay = fmaf(v.w, w3.y, ay);
        az = fmaf(v.w, w3.z, az); aw = fmaf(v.w, w3.w, aw);
    }

    const float cox = fminf(fmaxf(fmaxf(ax, 0.f) * 0.015625f, -128.f), 127.f);
    const float coy = fminf(fmaxf(fmaxf(ay, 0.f) * 0.015625f, -128.f), 127.f);
    const float coz = fminf(fmaxf(fmaxf(az, 0.f) * 0.015625f, -128.f), 127.f);
    const float cow = fminf(fmaxf(fmaxf(aw, 0.f) * 0.015625f, -128.f), 127.f);

    float tx = fmaf(cox, wl0.x, fmaf(coy, wl1.x, fmaf(coz, wl2.x, cow * wl3.x)));
    float ty = fmaf(cox, wl0.y, fmaf(coy, wl1.y, fmaf(coz, wl2.y, cow * wl3.y)));
    float tz = fmaf(cox, wl0.z, fmaf(coy, wl1.z, fmaf(coz, wl2.z, cow * wl3.z)));
    float tw = fmaf(cox, wl0.w, fmaf(coy, wl1.w, fmaf(coz, wl2.w, cow * wl3.w)));

    tx += __shfl_xor(tx, 1); ty += __shfl_xor(ty, 1);
    tz += __shfl_xor(tz, 1); tw += __shfl_xor(tw, 1);
    tx += __shfl_xor(tx, 2); ty += __shfl_xor(ty, 2);
    tz += __shfl_xor(tz, 2); tw += __shfl_xor(tw, 2);

    fx4 o;
    o.x = fminf(fmaxf(tx * 0.015625f, -128.f), 127.f);
    o.y = fminf(fmaxf(ty * 0.015625f, -128.f), 127.f);
    o.z = fminf(fmaxf(tz * 0.015625f, -128.f), 127.f);
    o.w = fminf(fmaxf(tw * 0.015625f, -128.f), 127.f);
    return o;
}

__global__ __launch_bounds__(256, 4) void surrogate_kernel(
    const float* __restrict__ img1, const float* __restrict__ img2,
    const float* __restrict__ Wc,   // (16,4) row-major
    const float* __restrict__ Wl,   // (16,4) row-major
    float* __restrict__ out,
    int B)
{
    const int lane = threadIdx.x & 63;
    const int p    = lane & 3;    // quadrant TL,TR,BL,BR
    const int mloc = lane >> 2;   // image index within 16-image group

    const float4* wc4 = (const float4*)Wc;
    const float4* wl4 = (const float4*)Wl;
    const float4 wl0 = wl4[p * 4 + 0];
    const float4 wl1 = wl4[p * 4 + 1];
    const float4 wl2 = wl4[p * 4 + 2];
    const float4 wl3 = wl4[p * 4 + 3];

    const int wavesPerBlock = blockDim.x >> 6;
    const int wid = (int)blockIdx.x * wavesPerBlock + ((int)threadIdx.x >> 6);
    const int nW  = (int)gridDim.x * wavesPerBlock;
    const long long total = 2LL * B;              // images across both inputs

    // Contiguous per-wave partition, rounded to 32-image granularity.
    long long per = (total + nW - 1) / nW;
    per = ((per + 31) >> 5) << 5;
    const long long start = (long long)wid * per;
    long long end = start + per;
    if (end > total) end = total;

    const int cb = (p & 1) + ((p >> 1) << 3);     // first chunk of quadrant p
    fx4* __restrict__ out4 = (fx4*)out;

    long long g0 = start;
    for (; g0 + 32 <= end; g0 += 32) {
        // Group boundaries are multiples of 16; B % 16 == 0, so the input
        // select is wave-uniform per group.
        const long long gA = g0 + mloc;
        const long long gB = g0 + 16 + mloc;
        const fx4* sA = (g0 < B)
            ? ((const fx4*)img1 + (gA << 4))
            : ((const fx4*)img2 + ((gA - B) << 4));
        const fx4* sB = (g0 + 16 < B)
            ? ((const fx4*)img1 + (gB << 4))
            : ((const fx4*)img2 + ((gB - B) << 4));

        // Issue all 8 loads before any compute: 8 in flight per lane.
        const fx4 a0 = ntload4(sA + cb + 0);
        const fx4 a1 = ntload4(sA + cb + 2);
        const fx4 a2 = ntload4(sA + cb + 4);
        const fx4 a3 = ntload4(sA + cb + 6);
        const fx4 b0 = ntload4(sB + cb + 0);
        const fx4 b1 = ntload4(sB + cb + 2);
        const fx4 b2 = ntload4(sB + cb + 4);
        const fx4 b3 = ntload4(sB + cb + 6);

        const fx4 oA = forward_quad(a0, a1, a2, a3, wc4, wl0, wl1, wl2, wl3);
        const fx4 oB = forward_quad(b0, b1, b2, b3, wc4, wl0, wl1, wl2, wl3);

        if (p == 0) {
            // out is (res1 | res2) back-to-back: flat float4 index == image id.
            __builtin_nontemporal_store(oA, out4 + gA);
            __builtin_nontemporal_store(oB, out4 + gB);
        }
    }
    // Tail: one remaining 16-image group (only if total/nW not 32-aligned).
    if (g0 + 16 <= end) {
        const long long gA = g0 + mloc;
        const fx4* sA = (g0 < B)
            ? ((const fx4*)img1 + (gA << 4))
            : ((const fx4*)img2 + ((gA - B) << 4));
        const fx4 a0 = ntload4(sA + cb + 0);
        const fx4 a1 = ntload4(sA + cb + 2);
        const fx4 a2 = ntload4(sA + cb + 4);
        const fx4 a3 = ntload4(sA + cb + 6);
        const fx4 oA = forward_quad(a0, a1, a2, a3, wc4, wl0, wl1, wl2, wl3);
        if (p == 0) __builtin_nontemporal_store(oA, out4 + gA);
    }
}

extern "C" void kernel_launch(void* const* d_in, const int* in_sizes, int n_in,
                              void* d_out, int out_size, void* d_ws, size_t ws_size,
                              hipStream_t stream) {
    const float* img1 = (const float*)d_in[0];
    const float* img2 = (const float*)d_in[1];
    const float* Wc   = (const float*)d_in[2];
    const float* Wl   = (const float*)d_in[3];
    float* out = (float*)d_out;

    const int B = in_sizes[0] / 64;   // images per input (1<<20)
    // 2048 blocks x 4 waves = 8192 waves; at B=1<<20 each wave owns a
    // contiguous 256-image (64 KiB) range = 8 iterations of 32 images.
    int blocks = (2 * B + 63) / 64;
    if (blocks > 2048) blocks = 2048;
    hipLaunchKernelGGL(surrogate_kernel, dim3(blocks), dim3(256), 0, stream,
                       img1, img2, Wc, Wl, out, B);
}

// Round 4
// 520.170 us; speedup vs baseline: 1.1246x; 1.1246x over previous
//
#include <hip/hip_runtime.h>

// Round-5 analysis: NT experiment (round-3/4) falsified the L3-thrash theory:
// FETCH_SIZE rose 258->404 MiB (bypass worked) but dur got WORSE (165->201us)
// -> L3 hits are cheaper than HBM; revert NT. The real finding: VGPR_Count=32
// means the compiler serialized the "8 loads in flight" (8 float4 alone need
// 32 regs) -> ~2KB outstanding per wave. Little's law: 3.45 TB/s / 256 CU =
// 13.5 GB/s/CU at ~34KB/CU in flight => ~2.5us effective latency. We are
// in-flight-bytes limited, NOT bandwidth limited. All three prior structures
// shared tiny flight depth -> same 165us plateau.
//
// Round-5 change: batch 4 groups (64 images) per wave iteration. Issue all
// 16 dwordx4 loads into live registers (64 VGPRs of data) before consuming;
// clang emits partial vmcnt waits -> ~12+ loads in flight under compute.
// launch_bounds(256,4) caps 128 VGPR -> 16 waves/CU -> ~250KB/CU in flight.
// Plain cached loads/stores (L3 hits are free bandwidth).
//
// Compute decomposition (verified, absmax 4.8e-7): 1 lane = 1 quadrant of 1
// image; matmul1 lane-local (Wc uniform -> s_load); matmul2 partial per
// quadrant, summed across 4 quadrant lanes via shfl_xor(1)+shfl_xor(2);
// lane p==0 stores the image's float4 result.

typedef float fx4 __attribute__((ext_vector_type(4)));

static __device__ __forceinline__ fx4 forward_quad(
    fx4 v0, fx4 v1, fx4 v2, fx4 v3,
    const float4* __restrict__ wc4,
    float4 wl0, float4 wl1, float4 wl2, float4 wl3)
{
    const fx4 vv[4] = {v0, v1, v2, v3};
    float ax = 0.f, ay = 0.f, az = 0.f, aw = 0.f;
#pragma unroll
    for (int j = 0; j < 4; ++j) {
        const fx4 v = vv[j];
        const float4 w0 = wc4[4 * j + 0];   // uniform address -> scalar load
        const float4 w1 = wc4[4 * j + 1];
        const float4 w2 = wc4[4 * j + 2];
        const float4 w3 = wc4[4 * j + 3];
        ax = fmaf(v.x, w0.x, ax); ay = fmaf(v.x, w0.y, ay);
        az = fmaf(v.x, w0.z, az); aw = fmaf(v.x, w0.w, aw);
        ax = fmaf(v.y, w1.x, ax); ay = fmaf(v.y, w1.y, ay);
        az = fmaf(v.y, w1.z, az); aw = fmaf(v.y, w1.w, aw);
        ax = fmaf(v.z, w2.x, ax); ay = fmaf(v.z, w2.y, ay);
        az = fmaf(v.z, w2.z, az); aw = fmaf(v.z, w2.w, aw);
        ax = fmaf(v.w, w3.x, ax); ay = fmaf(v.w, w3.y, ay);
        az = fmaf(v.w, w3.z, az); aw = fmaf(v.w, w3.w, aw);
    }

    const float cox = fminf(fmaxf(fmaxf(ax, 0.f) * 0.015625f, -128.f), 127.f);
    const float coy = fminf(fmaxf(fmaxf(ay, 0.f) * 0.015625f, -128.f), 127.f);
    const float coz = fminf(fmaxf(fmaxf(az, 0.f) * 0.015625f, -128.f), 127.f);
    const float cow = fminf(fmaxf(fmaxf(aw, 0.f) * 0.015625f, -128.f), 127.f);

    float tx = fmaf(cox, wl0.x, fmaf(coy, wl1.x, fmaf(coz, wl2.x, cow * wl3.x)));
    float ty = fmaf(cox, wl0.y, fmaf(coy, wl1.y, fmaf(coz, wl2.y, cow * wl3.y)));
    float tz = fmaf(cox, wl0.z, fmaf(coy, wl1.z, fmaf(coz, wl2.z, cow * wl3.z)));
    float tw = fmaf(cox, wl0.w, fmaf(coy, wl1.w, fmaf(coz, wl2.w, cow * wl3.w)));

    tx += __shfl_xor(tx, 1); ty += __shfl_xor(ty, 1);
    tz += __shfl_xor(tz, 1); tw += __shfl_xor(tw, 1);
    tx += __shfl_xor(tx, 2); ty += __shfl_xor(ty, 2);
    tz += __shfl_xor(tz, 2); tw += __shfl_xor(tw, 2);

    fx4 o;
    o.x = fminf(fmaxf(tx * 0.015625f, -128.f), 127.f);
    o.y = fminf(fmaxf(ty * 0.015625f, -128.f), 127.f);
    o.z = fminf(fmaxf(tz * 0.015625f, -128.f), 127.f);
    o.w = fminf(fmaxf(tw * 0.015625f, -128.f), 127.f);
    return o;
}

__global__ __launch_bounds__(256, 4) void surrogate_kernel(
    const float* __restrict__ img1, const float* __restrict__ img2,
    const float* __restrict__ Wc,   // (16,4) row-major
    const float* __restrict__ Wl,   // (16,4) row-major
    float* __restrict__ out,
    int B)
{
    const int lane = threadIdx.x & 63;
    const int p    = lane & 3;    // quadrant TL,TR,BL,BR
    const int mloc = lane >> 2;   // image index within 16-image group

    const float4* wc4 = (const float4*)Wc;
    const float4* wl4 = (const float4*)Wl;
    const float4 wl0 = wl4[p * 4 + 0];
    const float4 wl1 = wl4[p * 4 + 1];
    const float4 wl2 = wl4[p * 4 + 2];
    const float4 wl3 = wl4[p * 4 + 3];

    const int wavesPerBlock = blockDim.x >> 6;
    const int wid = (int)blockIdx.x * wavesPerBlock + ((int)threadIdx.x >> 6);
    const int nW  = (int)gridDim.x * wavesPerBlock;
    const long long total = 2LL * B;              // images across both inputs

    const int cb = (p & 1) + ((p >> 1) << 3);     // first chunk of quadrant p
    fx4* __restrict__ out4 = (fx4*)out;

    // ---- main: batches of 64 images (4 groups of 16), grid-stride ----
    // Requires B % 64 == 0 so a batch never straddles img1/img2 (B = 1<<20).
    const long long batchEnd = ((B & 63) == 0) ? (total & ~63LL) : 0;
    const long long step = (long long)nW << 6;

    for (long long g0 = (long long)wid << 6; g0 + 64 <= batchEnd; g0 += step) {
        const long long gb = (g0 < B) ? g0 : g0 - B;
        const fx4* __restrict__ src =
            ((g0 < B) ? (const fx4*)img1 : (const fx4*)img2) + (gb << 4);

        // Issue ALL 16 loads before any use: 16 KiB per wave in flight.
        fx4 d[4][4];
#pragma unroll
        for (int s = 0; s < 4; ++s) {
            const fx4* sp = src + (((s << 4) + mloc) << 4) + cb;
            d[s][0] = sp[0];
            d[s][1] = sp[2];
            d[s][2] = sp[4];
            d[s][3] = sp[6];
        }

        fx4 o[4];
#pragma unroll
        for (int s = 0; s < 4; ++s)
            o[s] = forward_quad(d[s][0], d[s][1], d[s][2], d[s][3],
                                wc4, wl0, wl1, wl2, wl3);

        if (p == 0) {
#pragma unroll
            for (int s = 0; s < 4; ++s)
                out4[g0 + (s << 4) + mloc] = o[s];
        }
    }

    // ---- tail / fallback: one 16-image group at a time ----
    for (long long g0 = batchEnd + ((long long)wid << 4); g0 + 16 <= total;
         g0 += (long long)nW << 4) {
        const long long gA = g0 + mloc;
        const fx4* sA = (g0 < B)
            ? ((const fx4*)img1 + (gA << 4))
            : ((const fx4*)img2 + ((gA - B) << 4));
        const fx4 v0 = sA[cb + 0];
        const fx4 v1 = sA[cb + 2];
        const fx4 v2 = sA[cb + 4];
        const fx4 v3 = sA[cb + 6];
        const fx4 oA = forward_quad(v0, v1, v2, v3, wc4, wl0, wl1, wl2, wl3);
        if (p == 0) out4[gA] = oA;
    }
}

extern "C" void kernel_launch(void* const* d_in, const int* in_sizes, int n_in,
                              void* d_out, int out_size, void* d_ws, size_t ws_size,
                              hipStream_t stream) {
    const float* img1 = (const float*)d_in[0];
    const float* img2 = (const float*)d_in[1];
    const float* Wc   = (const float*)d_in[2];
    const float* Wl   = (const float*)d_in[3];
    float* out = (float*)d_out;

    const int B = in_sizes[0] / 64;   // images per input (1<<20)
    // 2048 blocks x 4 waves = 8192 waves; at B=1<<20 each wave runs 4
    // batches of 64 images (16 KiB contiguous per batch).
    int blocks = (2 * B + 63) / 64;
    if (blocks > 2048) blocks = 2048;
    hipLaunchKernelGGL(surrogate_kernel, dim3(blocks), dim3(256), 0, stream,
                       img1, img2, Wc, Wl, out, B);
}